// Round 5
// baseline (153.566 us; speedup 1.0000x reference)
//
#include <hip/hip_runtime.h>

// ---------------------------------------------------------------------------
// Compile-time Cayley tables for PGA G(3,0,1), basis ordered by grade:
// idx: 0:1 1:e0 2:e1 3:e2 4:e3 5:e01 6:e02 7:e03 8:e12 9:e13 10:e23
//      11:e012 12:e013 13:e023 14:e123 15:e0123
// Blade as 4-bit mask: e0=bit0, e1=bit1, e2=bit2, e3=bit3.
// ---------------------------------------------------------------------------
namespace ga {

constexpr int MASK[16]        = {0,1,2,4,8,3,5,9,6,10,12,7,11,13,14,15};
constexpr int IDX_OF_MASK[16] = {0,1,2,5,3,6,8,11,4,7,9,12,10,13,14,15};

constexpr int popc(int v) { int c = 0; while (v) { c += v & 1; v >>= 1; } return c; }

constexpr int reorder_sign(int a, int b) {
    int s = 0; int t = a >> 1;
    while (t) { s += popc(t & b); t >>= 1; }
    return (s & 1) ? -1 : 1;
}

struct Term { signed char i, j, k, s; };

// Geometric product, metric (0,1,1,1): 192 nonzero terms.
struct GPTab { Term t[192]; };
constexpr GPTab build_gp() {
    GPTab T{}; int n = 0;
    for (int i = 0; i < 16; i++)
        for (int j = 0; j < 16; j++) {
            int a = MASK[i], b = MASK[j];
            if (a & b & 1) continue;                 // e0^2 = 0
            T.t[n].i = (signed char)i;
            T.t[n].j = (signed char)j;
            T.t[n].k = (signed char)IDX_OF_MASK[a ^ b];
            T.t[n].s = (signed char)reorder_sign(a, b);
            n++;
        }
    return T;
}

// Join (sans ref scale): dual(dual(x) ^ dual(y)) folded to 81 terms.
struct JNTab { Term t[81]; };
constexpr JNTab build_join() {
    JNTab T{}; int n = 0;
    int didx[16] = {}, dsgn[16] = {};
    for (int i = 0; i < 16; i++) {
        int a = MASK[i], c = (~a) & 0xF;
        didx[i] = IDX_OF_MASK[c];
        dsgn[i] = reorder_sign(a, c);
    }
    for (int i = 0; i < 16; i++)
        for (int j = 0; j < 16; j++) {
            int p = didx[i], q = didx[j];
            int a = MASK[p], b = MASK[q];
            if (a & b) continue;
            int m = IDX_OF_MASK[a | b];
            int k = didx[m];
            int s = dsgn[i] * dsgn[j] * dsgn[m] * reorder_sign(a, b);
            T.t[n].i = (signed char)i;
            T.t[n].j = (signed char)j;
            T.t[n].k = (signed char)k;
            T.t[n].s = (signed char)s;
            n++;
        }
    return T;
}

constexpr GPTab G = build_gp();
constexpr JNTab J = build_join();

} // namespace ga

// ---------------------------------------------------------------------------
// R12: independent waves + non-temporal output stream.
//
// R7-R11 ladder is pinned at 46-52 us across occupancy 15->38%, pipeline
// on/off, compute split on/off. Arithmetic: ~3.7K cy/chunk/CU with only
// ~300-600 cy of busy work -> waves idle ~90%, yet NO throughput counter is
// near its ceiling (HBM 30%, LDS 7%, L1 ~5%). Latency-dominated AND
// occupancy-insensitive => the read path is slow for a structural reason:
// FETCH_SIZE ~50 MB on EVERY dispatch (warm or cold) although the 100 MB
// input set fits the 256 MB L3 — the 67 MB/dispatch output stream allocates
// through L2/L3 and keeps evicting the inputs. Reads then miss to HBM
// (~900 cy) with deep queuing that 20 waves/CU cannot hide.
//
// R12 changes:
//   1. Output stores are NON-TEMPORAL (MUBUF nt): written once, never read
//      -> don't allocate in L2/L3 -> inputs stay L3-resident across bench
//      iterations; read latency drops to L3-hit.
//   2. Zero inter-wave coupling: 4-wave blocks, each wave owns one 64-pt
//      chunk and a private 8 KB overlay region. No barriers at all.
//      Loads: per-lane strided float4 (R10 proved FETCH == input bytes).
//      Stores: overlay transpose + cooperative full-line stores (R8/R11
//      proved WRITE == output bytes, conflict-free with stride-32 XOR).
//   3. LDS 32 KB/block -> 5 blocks/CU = 20 waves/CU; __launch_bounds__
//      (256,5) caps VGPR at ~102 (live ~70 — R9's forced-40 spill avoided).
// ---------------------------------------------------------------------------

typedef float f32x4 __attribute__((ext_vector_type(4)));

__global__ __launch_bounds__(256, 5)
void MVGeometricBilinear_kernel(const float* __restrict__ x,
                                const float* __restrict__ y,
                                const float* __restrict__ ref,
                                float* __restrict__ out,
                                int nchunks)
{
    __shared__ __align__(16) float lds[4][2048];   // 8 KB per wave, private

    const int lane = threadIdx.x & 63;
    const int wid  = threadIdx.x >> 6;
    const long chunk = (long)blockIdx.x * 4 + wid;
    if (chunk >= nchunks) return;
    const long pt = chunk * 64 + lane;

    // ---- per-lane loads: 4x dwordx4 each for x,y; 1 dword for ref_e0123 ----
    const float4* xp = reinterpret_cast<const float4*>(x) + pt * 4;
    const float4* yp = reinterpret_cast<const float4*>(y) + pt * 4;
    float xx[16], yy[16];
#pragma unroll
    for (int k = 0; k < 4; k++) {
        const float4 vx = xp[k];
        const float4 vy = yp[k];
        xx[4*k+0] = vx.x; xx[4*k+1] = vx.y; xx[4*k+2] = vx.z; xx[4*k+3] = vx.w;
        yy[4*k+0] = vy.x; yy[4*k+1] = vy.y; yy[4*k+2] = vy.z; yy[4*k+3] = vy.w;
    }
    const float r = ref[pt * 16 + 15];

    float* lo = &lds[wid][0];
    const int px = lane & 7;

    // ---- phase 1: geometric product (192 terms) -> overlay quarters 0..3 ----
    {
        float gp[16] = {0.f,0.f,0.f,0.f,0.f,0.f,0.f,0.f,
                        0.f,0.f,0.f,0.f,0.f,0.f,0.f,0.f};
#pragma unroll
        for (int t = 0; t < 192; t++) {
            const int ti = ga::G.t[t].i, tj = ga::G.t[t].j, tk = ga::G.t[t].k;
            const float v = xx[ti] * yy[tj];
            if (ga::G.t[t].s > 0) gp[tk] += v; else gp[tk] -= v;
        }
#pragma unroll
        for (int q = 0; q < 4; q++)
            *reinterpret_cast<float4*>(lo + lane * 32 + ((q ^ px) << 2)) =
                make_float4(gp[4*q+0], gp[4*q+1], gp[4*q+2], gp[4*q+3]);
    }

    // ---- phase 2: join (81 terms), scale by ref -> overlay quarters 4..7 ----
    {
        float jn[16] = {0.f,0.f,0.f,0.f,0.f,0.f,0.f,0.f,
                        0.f,0.f,0.f,0.f,0.f,0.f,0.f,0.f};
#pragma unroll
        for (int t = 0; t < 81; t++) {
            const int ti = ga::J.t[t].i, tj = ga::J.t[t].j, tk = ga::J.t[t].k;
            const float v = xx[ti] * yy[tj];
            if (ga::J.t[t].s > 0) jn[tk] += v; else jn[tk] -= v;
        }
#pragma unroll
        for (int q = 0; q < 4; q++)
            *reinterpret_cast<float4*>(lo + lane * 32 + (((q + 4) ^ px) << 2)) =
                make_float4(r*jn[4*q+0], r*jn[4*q+1], r*jn[4*q+2], r*jn[4*q+3]);
    }

    // All 64 lanes of THIS wave wrote the overlay; same instruction stream ->
    // lgkmcnt(0) orders every lane's ds_write before the gathers below.
    // "memory" clobber stops the compiler reordering across (R3 lesson).
    asm volatile("s_waitcnt lgkmcnt(0)" ::: "memory");

    // ---- cooperative full-line stores, NON-TEMPORAL: 8 x dwordx4/lane ----
    // g-th float4 of the chunk = point p=g>>3, quarter q=g&7 at swizzled slot.
    f32x4* go = reinterpret_cast<f32x4*>(out) + chunk * 512;
#pragma unroll
    for (int c = 0; c < 8; c++) {
        const int g = c * 64 + lane;               // lane-consecutive -> 1 KB/instr
        const int p = g >> 3, q = g & 7;
        const f32x4 v = *reinterpret_cast<const f32x4*>(
                            lo + p * 32 + ((q ^ (p & 7)) << 2));
        __builtin_nontemporal_store(v, go + g);
    }
}

// Tail path (npts not divisible by 64) — scalar per-thread, same math.
__global__ __launch_bounds__(64)
void MVGeometricBilinear_tail(const float* __restrict__ x,
                              const float* __restrict__ y,
                              const float* __restrict__ ref,
                              float* __restrict__ out,
                              int start, int npts)
{
    int pt = start + blockIdx.x * 64 + threadIdx.x;
    if (pt >= npts) return;
    float xx[16], yy[16];
#pragma unroll
    for (int k = 0; k < 16; k++) { xx[k] = x[(size_t)pt*16+k]; yy[k] = y[(size_t)pt*16+k]; }
    const float r = ref[(size_t)pt*16+15];
    float gp[16] = {}, jn[16] = {};
#pragma unroll
    for (int t = 0; t < 192; t++) {
        const float v = xx[ga::G.t[t].i] * yy[ga::G.t[t].j];
        if (ga::G.t[t].s > 0) gp[ga::G.t[t].k] += v; else gp[ga::G.t[t].k] -= v;
    }
#pragma unroll
    for (int t = 0; t < 81; t++) {
        const float v = xx[ga::J.t[t].i] * yy[ga::J.t[t].j];
        if (ga::J.t[t].s > 0) jn[ga::J.t[t].k] += v; else jn[ga::J.t[t].k] -= v;
    }
#pragma unroll
    for (int k = 0; k < 16; k++) out[(size_t)pt*32+k] = gp[k];
#pragma unroll
    for (int k = 0; k < 16; k++) out[(size_t)pt*32+16+k] = r * jn[k];
}

extern "C" void kernel_launch(void* const* d_in, const int* in_sizes, int n_in,
                              void* d_out, int out_size, void* d_ws, size_t ws_size,
                              hipStream_t stream) {
    const float* x   = (const float*)d_in[0];
    const float* y   = (const float*)d_in[1];
    const float* ref = (const float*)d_in[2];
    float* out = (float*)d_out;

    const int npts    = in_sizes[0] / 16;     // B*T = 524288
    const int nchunks = npts / 64;            // 8192

    if (nchunks > 0) {
        const int blocks = (nchunks + 3) / 4; // 2048; 4 waves/block, 1 chunk/wave
        MVGeometricBilinear_kernel<<<blocks, 256, 0, stream>>>(
            x, y, ref, out, nchunks);
    }

    const int rem = npts - nchunks * 64;      // 0 for this shape
    if (rem > 0) {
        MVGeometricBilinear_tail<<<(rem + 63) / 64, 64, 0, stream>>>(
            x, y, ref, out, nchunks * 64, npts);
    }
}

// Round 6
// 147.184 us; speedup vs baseline: 1.0434x; 1.0434x over previous
//
#include <hip/hip_runtime.h>

// ---------------------------------------------------------------------------
// Compile-time Cayley tables for PGA G(3,0,1), basis ordered by grade:
// idx: 0:1 1:e0 2:e1 3:e2 4:e3 5:e01 6:e02 7:e03 8:e12 9:e13 10:e23
//      11:e012 12:e013 13:e023 14:e123 15:e0123
// Blade as 4-bit mask: e0=bit0, e1=bit1, e2=bit2, e3=bit3.
// ---------------------------------------------------------------------------
namespace ga {

constexpr int MASK[16]        = {0,1,2,4,8,3,5,9,6,10,12,7,11,13,14,15};
constexpr int IDX_OF_MASK[16] = {0,1,2,5,3,6,8,11,4,7,9,12,10,13,14,15};

constexpr int popc(int v) { int c = 0; while (v) { c += v & 1; v >>= 1; } return c; }

constexpr int reorder_sign(int a, int b) {
    int s = 0; int t = a >> 1;
    while (t) { s += popc(t & b); t >>= 1; }
    return (s & 1) ? -1 : 1;
}

struct Term { signed char i, j, k, s; };

// Geometric product, metric (0,1,1,1): 192 nonzero terms.
struct GPTab { Term t[192]; };
constexpr GPTab build_gp() {
    GPTab T{}; int n = 0;
    for (int i = 0; i < 16; i++)
        for (int j = 0; j < 16; j++) {
            int a = MASK[i], b = MASK[j];
            if (a & b & 1) continue;                 // e0^2 = 0
            T.t[n].i = (signed char)i;
            T.t[n].j = (signed char)j;
            T.t[n].k = (signed char)IDX_OF_MASK[a ^ b];
            T.t[n].s = (signed char)reorder_sign(a, b);
            n++;
        }
    return T;
}

// Join (sans ref scale): dual(dual(x) ^ dual(y)) folded to 81 terms.
struct JNTab { Term t[81]; };
constexpr JNTab build_join() {
    JNTab T{}; int n = 0;
    int didx[16] = {}, dsgn[16] = {};
    for (int i = 0; i < 16; i++) {
        int a = MASK[i], c = (~a) & 0xF;
        didx[i] = IDX_OF_MASK[c];
        dsgn[i] = reorder_sign(a, c);
    }
    for (int i = 0; i < 16; i++)
        for (int j = 0; j < 16; j++) {
            int p = didx[i], q = didx[j];
            int a = MASK[p], b = MASK[q];
            if (a & b) continue;
            int m = IDX_OF_MASK[a | b];
            int k = didx[m];
            int s = dsgn[i] * dsgn[j] * dsgn[m] * reorder_sign(a, b);
            T.t[n].i = (signed char)i;
            T.t[n].j = (signed char)j;
            T.t[n].k = (signed char)k;
            T.t[n].s = (signed char)s;
            n++;
        }
    return T;
}

constexpr GPTab G = build_gp();
constexpr JNTab J = build_join();

} // namespace ga

// ---------------------------------------------------------------------------
// R13: pipeline + sliding-window order + minimal bytes (R7/R8/R11/R12 synth).
//
// Empirical law from R7-R12: dur ~= HBM_bytes / (2.6 +- 0.3 TB/s) across SIX
// structural variants (occupancy 15-38%, pipeline on/off, nt on/off). R12's
// nt stores amplified WRITE 1.5x and raised FETCH -> reverted. The one
// untested combination: R8's sliding contiguous address window (its win over
// R7) TOGETHER WITH R7's counted-vmcnt DMA pipeline (its overlap), at the
// byte-minimal traffic of R8.
//
//   * 1-wave blocks, no barriers. Grid = 2560 (10 blocks/CU at 16 KB LDS);
//     grid-stride gstride=2560: all waves walk ONE sliding ~10 MB window
//     (page-friendly, like R8), each wave pipelines across its NITER chunks.
//   * Double-buffered DMA (8 x global_load_lds 16B per chunk) with R11's
//     verified source pre-swizzle -> conflict-free b128 frag reads.
//   * ref: NITER per-lane dword loads in the prologue (oldest ops; drained
//     by the first wait). No rbuf -> LDS = 2 x 8 KB = 16384 B exactly.
//   * Counted vmcnt, never 0 mid-loop. Issue order per iter i:
//     [G_{i+1}: 8 DMA] W(i) [frags][compute][overlay][S_i: 8 stores].
//     At W(i>=1): newer-than-G_i = S_{i-1}(8) + G_{i+1}(8) = 16 -> vmcnt(16)
//     (stores AND next DMA stay in flight). W(0): vmcnt(8). No-prefetch
//     tails: vmcnt(8) / vmcnt(0).
//   * Overlay: R12's stride-32 XOR (q^(p&7)) over the consumed buffer —
//     2048 floats = exactly one output chunk; conflict-free writes+gathers;
//     cooperative full-line dwordx4 stores (regular, NOT nt).
//   * LDS safety w/o barriers (single wave): LDS ops execute in issue order
//     per wave; gather ds_reads are lgkm-waited before their stores issue,
//     which precedes the next iteration's DMA issue -> no WAR with async
//     DMA write-back. Compiler fences ("" ::: "memory") pin the phases.
// ---------------------------------------------------------------------------

typedef const __attribute__((address_space(1))) void* gas_ptr;
typedef __attribute__((address_space(3))) void*       las_ptr;

constexpr int NITER = 4;

__global__ __launch_bounds__(64, 2)
void MVGeometricBilinear_kernel(const float* __restrict__ x,
                                const float* __restrict__ y,
                                const float* __restrict__ ref,
                                float* __restrict__ out,
                                int nchunks, int gstride)
{
    __shared__ __align__(16) float buf[2][2048];

    const int lane = threadIdx.x;              // block == 1 wave
    const long chunk0 = blockIdx.x;
    if (chunk0 >= nchunks) return;

    // ---- ref prologue: NITER per-lane dword loads (oldest vm ops) ----
    float rr[NITER];
    {
        long c = chunk0;
#pragma unroll
        for (int it = 0; it < NITER; ++it) {
            if (c < nchunks) rr[it] = ref[(c * 64 + lane) * 16 + 15];
            c += gstride;
        }
    }

    // ---- R11-verified swizzle offsets ----
    // DMA op k lands lane L at LDS float4-slot (k*64 + L). Slot-group s of
    // point p holds global group j=(s-t)&3, t=(p>>1)&3 (via swizzled global
    // source); frag read for group k at slot-group (k+t)&3. Conflict-free.
    int srcoff[4];   // global float4 offset within the chunk for DMA op k
    int fragoff[4];  // LDS word addr of my point's group k (x; y = +1024)
#pragma unroll
    for (int k = 0; k < 4; ++k) {
        const int slot = k * 64 + lane;
        const int j = ((slot & 3) - ((slot >> 3) & 3)) & 3;
        srcoff[k] = (slot & ~3) | j;
        const int s = (k + ((lane >> 1) & 3)) & 3;
        fragoff[k] = lane * 16 + (s << 2);
    }

    const float4* gx = reinterpret_cast<const float4*>(x);
    const float4* gy = reinterpret_cast<const float4*>(y);

    auto dma = [&](long c, int b) {            // 8 vm ops
#pragma unroll
        for (int k = 0; k < 4; ++k)
            __builtin_amdgcn_global_load_lds((gas_ptr)(gx + c * 256 + srcoff[k]),
                                             (las_ptr)(&buf[b][k * 256]), 16, 0, 0);
#pragma unroll
        for (int k = 0; k < 4; ++k)
            __builtin_amdgcn_global_load_lds((gas_ptr)(gy + c * 256 + srcoff[k]),
                                             (las_ptr)(&buf[b][1024 + k * 256]), 16, 0, 0);
    };

    long chunk = chunk0;
    int cur = 0;
    dma(chunk, 0);                             // G_0

#pragma unroll
    for (int it = 0; it < NITER; ++it) {
        const long next = chunk + gstride;
        const bool pf = (it + 1 < NITER) && (next < nchunks);
        if (pf) dma(next, cur ^ 1);            // G_{i+1} into the other buffer

        // Drain G_i (and, transitively, all ref loads). Keep S_{i-1} and
        // G_{i+1} in flight: newer-than-G_i = 8 stores + 8 DMA.
        if (it == 0) {
            if (pf) asm volatile("s_waitcnt vmcnt(8)" ::: "memory");
            else    asm volatile("s_waitcnt vmcnt(0)" ::: "memory");
        } else {
            if (pf) asm volatile("s_waitcnt vmcnt(16)" ::: "memory");
            else    asm volatile("s_waitcnt vmcnt(8)" ::: "memory");
        }

        // ---- fragments: 8 x ds_read_b128, swizzle-conflict-free ----
        float xx[16], yy[16];
#pragma unroll
        for (int k = 0; k < 4; ++k) {
            const float4 vx = *reinterpret_cast<const float4*>(&buf[cur][fragoff[k]]);
            const float4 vy = *reinterpret_cast<const float4*>(&buf[cur][1024 + fragoff[k]]);
            xx[4*k+0] = vx.x; xx[4*k+1] = vx.y; xx[4*k+2] = vx.z; xx[4*k+3] = vx.w;
            yy[4*k+0] = vy.x; yy[4*k+1] = vy.y; yy[4*k+2] = vy.z; yy[4*k+3] = vy.w;
        }
        const float r = rr[it];

        // ---- compute: full 192 + 81 terms ----
        float gp[16] = {0.f,0.f,0.f,0.f,0.f,0.f,0.f,0.f,
                        0.f,0.f,0.f,0.f,0.f,0.f,0.f,0.f};
        float jn[16] = {0.f,0.f,0.f,0.f,0.f,0.f,0.f,0.f,
                        0.f,0.f,0.f,0.f,0.f,0.f,0.f,0.f};
#pragma unroll
        for (int t = 0; t < 192; t++) {
            const int ti = ga::G.t[t].i, tj = ga::G.t[t].j, tk = ga::G.t[t].k;
            const float v = xx[ti] * yy[tj];
            if (ga::G.t[t].s > 0) gp[tk] += v; else gp[tk] -= v;
        }
#pragma unroll
        for (int t = 0; t < 81; t++) {
            const int ti = ga::J.t[t].i, tj = ga::J.t[t].j, tk = ga::J.t[t].k;
            const float v = xx[ti] * yy[tj];
            if (ga::J.t[t].s > 0) jn[tk] += v; else jn[tk] -= v;
        }

        // Fence: frag reads above, overlay writes below (cross-lane WAR
        // invisible to per-thread alias analysis — R3 lesson).
        asm volatile("" ::: "memory");

        // ---- overlay: stride 32 + XOR(q^(lane&7)) over consumed buffer ----
        float* lo = &buf[cur][0];
        const int px = lane & 7;
#pragma unroll
        for (int q = 0; q < 4; q++)
            *reinterpret_cast<float4*>(lo + lane * 32 + ((q ^ px) << 2)) =
                make_float4(gp[4*q+0], gp[4*q+1], gp[4*q+2], gp[4*q+3]);
#pragma unroll
        for (int q = 0; q < 4; q++)
            *reinterpret_cast<float4*>(lo + lane * 32 + (((q + 4) ^ px) << 2)) =
                make_float4(r*jn[4*q+0], r*jn[4*q+1], r*jn[4*q+2], r*jn[4*q+3]);

        asm volatile("s_waitcnt lgkmcnt(0)" ::: "memory");

        // ---- cooperative full-line stores: 8 x dwordx4/lane (S_i) ----
        float4* go = reinterpret_cast<float4*>(out) + chunk * 512;
#pragma unroll
        for (int c = 0; c < 8; c++) {
            const int g = c * 64 + lane;       // lane-consecutive -> 1 KB/instr
            const int p = g >> 3, q = g & 7;
            go[g] = *reinterpret_cast<const float4*>(
                        lo + p * 32 + ((q ^ (p & 7)) << 2));
        }

        // Fence: overlay gathers stay above the next iteration's DMA issue.
        asm volatile("" ::: "memory");

        if (!pf) break;
        cur ^= 1;
        chunk = next;
    }
}

// Tail path (npts not divisible by 64) — scalar per-thread, same math.
__global__ __launch_bounds__(64)
void MVGeometricBilinear_tail(const float* __restrict__ x,
                              const float* __restrict__ y,
                              const float* __restrict__ ref,
                              float* __restrict__ out,
                              int start, int npts)
{
    int pt = start + blockIdx.x * 64 + threadIdx.x;
    if (pt >= npts) return;
    float xx[16], yy[16];
#pragma unroll
    for (int k = 0; k < 16; k++) { xx[k] = x[(size_t)pt*16+k]; yy[k] = y[(size_t)pt*16+k]; }
    const float r = ref[(size_t)pt*16+15];
    float gp[16] = {}, jn[16] = {};
#pragma unroll
    for (int t = 0; t < 192; t++) {
        const float v = xx[ga::G.t[t].i] * yy[ga::G.t[t].j];
        if (ga::G.t[t].s > 0) gp[ga::G.t[t].k] += v; else gp[ga::G.t[t].k] -= v;
    }
#pragma unroll
    for (int t = 0; t < 81; t++) {
        const float v = xx[ga::J.t[t].i] * yy[ga::J.t[t].j];
        if (ga::J.t[t].s > 0) jn[ga::J.t[t].k] += v; else jn[ga::J.t[t].k] -= v;
    }
#pragma unroll
    for (int k = 0; k < 16; k++) out[(size_t)pt*32+k] = gp[k];
#pragma unroll
    for (int k = 0; k < 16; k++) out[(size_t)pt*32+16+k] = r * jn[k];
}

extern "C" void kernel_launch(void* const* d_in, const int* in_sizes, int n_in,
                              void* d_out, int out_size, void* d_ws, size_t ws_size,
                              hipStream_t stream) {
    const float* x   = (const float*)d_in[0];
    const float* y   = (const float*)d_in[1];
    const float* ref = (const float*)d_in[2];
    float* out = (float*)d_out;

    const int npts    = in_sizes[0] / 16;     // B*T = 524288
    const int nchunks = npts / 64;            // 8192

    if (nchunks > 0) {
        // 10 blocks/CU x 256 CU = 2560; each wave walks <= NITER chunks at
        // stride 2560 -> one sliding contiguous address window.
        int blocks = nchunks < 2560 ? nchunks : 2560;
        const int need = (nchunks + NITER - 1) / NITER;
        if (blocks < need) blocks = need;
        MVGeometricBilinear_kernel<<<blocks, 64, 0, stream>>>(
            x, y, ref, out, nchunks, blocks);
    }

    const int rem = npts - nchunks * 64;      // 0 for this shape
    if (rem > 0) {
        MVGeometricBilinear_tail<<<(rem + 63) / 64, 64, 0, stream>>>(
            x, y, ref, out, nchunks * 64, npts);
    }
}